// Round 4
// baseline (173.661 us; speedup 1.0000x reference)
//
#include <hip/hip_runtime.h>
#include <stdint.h>

#define TPB 256
#define MMB 1024        // minmax grid blocks (also # of mm partial pairs)
#define SCB 1024        // score grid blocks
#define WELEM 2048      // elements per wave-chunk
#define NG (WELEM / 32) // 32-elem groups per chunk

// d_ws float layout:
//  [OFF_MM + 2b]          : minmax block partials {min,max}, b = 0..mmb-1
//  [OFF_PART + b*128 + k] : per-score-block partial loss sums
#define OFF_MM     256
#define OFF_PART   4096

__global__ __launch_bounds__(TPB) void k_minmax(const float* __restrict__ x, int n,
                                                float* __restrict__ mm) {
    int n4 = n >> 2;
    const float4* x4 = (const float4*)x;
    float mn = INFINITY, mx = -INFINITY;
    int idx = blockIdx.x * TPB + threadIdx.x;
    int stride = gridDim.x * TPB;
    for (int i = idx; i < n4; i += stride) {
        float4 v = x4[i];
        mn = fminf(mn, fminf(fminf(v.x, v.y), fminf(v.z, v.w)));
        mx = fmaxf(mx, fmaxf(fmaxf(v.x, v.y), fmaxf(v.z, v.w)));
    }
    for (int i = (n4 << 2) + idx; i < n; i += stride) {
        float v = x[i];
        mn = fminf(mn, v);
        mx = fmaxf(mx, v);
    }
    #pragma unroll
    for (int m = 32; m; m >>= 1) {
        mn = fminf(mn, __shfl_xor(mn, m, 64));
        mx = fmaxf(mx, __shfl_xor(mx, m, 64));
    }
    __shared__ float smn[4], smx[4];
    int wv = threadIdx.x >> 6;
    if ((threadIdx.x & 63) == 0) { smn[wv] = mn; smx[wv] = mx; }
    __syncthreads();
    if (threadIdx.x == 0) {
        mn = fminf(fminf(smn[0], smn[1]), fminf(smn[2], smn[3]));
        mx = fmaxf(fmaxf(smx[0], smx[1]), fmaxf(smx[2], smx[3]));
        mm[2 * blockIdx.x + 0] = mn;
        mm[2 * blockIdx.x + 1] = mx;
    }
}

// exact reference fp32 order; must be IDENTICAL in k_score and k_final
__device__ __forceinline__ float4 cand_params(int k, float xmin, float xmax,
                                              float* nmin_out, float* nmax_out) {
    float xrange = xmax - xmin;
    int ii = k >> 4;                       // 0..7  (i = ii+1)
    float zpf = (float)(k & 15);
    float tmp_max = xrange / 8.0f * (float)(ii + 1);
    float tmp_delta = tmp_max / 15.0f;
    float shift = zpf * tmp_delta;
    float new_min = fmaxf(0.0f - shift, xmin);
    float new_max = fminf(tmp_max - shift, xmax);
    float min_neg = fminf(new_min, 0.0f);
    float max_pos = fmaxf(new_max, 0.0f);
    float scale = fmaxf((max_pos - min_neg) / 15.0f, 1e-8f);
    float zp = 0.0f - rintf(min_neg / scale);
    zp = fminf(fmaxf(zp, 0.0f), 15.0f);
    float4 p;
    p.x = 1.0f / scale;      // inv_s
    p.y = scale;             // s
    p.z = 0.0f - zp;         // lo
    p.w = 15.0f - zp;        // hi
    *nmin_out = new_min;
    *nmax_out = new_max;
    return p;
}

#define QUANT1(xv) { \
    float t0_ = (xv) * p0.x; float r0_ = rintf(t0_); \
    float c0_ = __builtin_amdgcn_fmed3f(r0_, p0.z, p0.w); \
    float d0_ = __builtin_fmaf(c0_, p0.y, -(xv)); \
    a0 = __builtin_fmaf(d0_, d0_, a0); \
    float t1_ = (xv) * p1.x; float r1_ = rintf(t1_); \
    float c1_ = __builtin_amdgcn_fmed3f(r1_, p1.z, p1.w); \
    float d1_ = __builtin_fmaf(c1_, p1.y, -(xv)); \
    a1 = __builtin_fmaf(d1_, d1_, a1); }
#define QUANT4(V) { QUANT1(V.x) QUANT1(V.y) QUANT1(V.z) QUANT1(V.w) }
#define COMP8(V0,V1,V2,V3,V4,V5,V6,V7) { QUANT4(V0) QUANT4(V1) QUANT4(V2) QUANT4(V3) \
                                         QUANT4(V4) QUANT4(V5) QUANT4(V6) QUANT4(V7) }
#define LOAD8(P,V0,V1,V2,V3,V4,V5,V6,V7) { V0=(P)[0];V1=(P)[1];V2=(P)[2];V3=(P)[3]; \
                                           V4=(P)[4];V5=(P)[5];V6=(P)[6];V7=(P)[7]; }

// candidate-per-lane scoring. Params derived per-block from mm partials (no
// separate k_params kernel). Broadcast x-reads forced onto the VECTOR memory
// path (asm VGPR zero defeats uniformity/scalarization) so 8 loads/wave stay
// in flight under vmcnt while the previous group computes.
__global__ __launch_bounds__(TPB, 4) void k_score(const float* __restrict__ x, int n,
                                                  const float* __restrict__ mm, int mmb,
                                                  float* __restrict__ part, int nwc) {
    __shared__ float wsum[4][128];
    __shared__ float smn[4], smx[4];
    int tid = threadIdx.x, lane = tid & 63;
    int wv = __builtin_amdgcn_readfirstlane(threadIdx.x >> 6);

    // block-local reduce of minmax partials (order-free: fmin/fmax exact)
    float mn = INFINITY, mx = -INFINITY;
    for (int e = tid; e < mmb; e += TPB) {
        mn = fminf(mn, mm[2 * e + 0]);
        mx = fmaxf(mx, mm[2 * e + 1]);
    }
    #pragma unroll
    for (int m = 32; m; m >>= 1) {
        mn = fminf(mn, __shfl_xor(mn, m, 64));
        mx = fmaxf(mx, __shfl_xor(mx, m, 64));
    }
    if (lane == 0) { smn[wv] = mn; smx[wv] = mx; }
    __syncthreads();
    float xmin = fminf(fminf(smn[0], smn[1]), fminf(smn[2], smn[3]));
    float xmax = fmaxf(fmaxf(smx[0], smx[1]), fmaxf(smx[2], smx[3]));
    float dum0, dum1;
    float4 p0 = cand_params(2 * lane + 0, xmin, xmax, &dum0, &dum1);
    float4 p1 = cand_params(2 * lane + 1, xmin, xmax, &dum0, &dum1);
    float a0 = 0.0f, a1 = 0.0f;
    long nl = (long)n;

    // divergence decoy: VGPR zero the compiler can't prove uniform
    int lzero;
    asm("v_mov_b32 %0, 0" : "=v"(lzero));

    for (int wc = blockIdx.x * 4 + wv; wc < nwc; wc += gridDim.x * 4) {
        long base = (long)wc * WELEM;
        if (base + WELEM <= nl) {
            const float4* __restrict__ xp = (const float4*)(x + base) + lzero;
            float4 A0,A1,A2,A3,A4,A5,A6,A7;
            float4 B0,B1,B2,B3,B4,B5,B6,B7;
            LOAD8(xp, A0,A1,A2,A3,A4,A5,A6,A7)
            #pragma unroll 1
            for (int g = 0; g < NG; g += 2) {
                const float4* q1 = xp + (g + 1) * 8;
                LOAD8(q1, B0,B1,B2,B3,B4,B5,B6,B7)
                COMP8(A0,A1,A2,A3,A4,A5,A6,A7)
                int g2 = (g + 2 < NG) ? (g + 2) : (NG - 1);  // harmless reload on last iter
                const float4* q2 = xp + g2 * 8;
                LOAD8(q2, A0,A1,A2,A3,A4,A5,A6,A7)
                COMP8(B0,B1,B2,B3,B4,B5,B6,B7)
            }
        } else {
            for (long e = base; e < base + WELEM; ++e) {
                float xv = (e < nl) ? x[e] : 0.0f;  // pad scores 0 everywhere
                QUANT1(xv)
            }
        }
    }
    wsum[wv][2 * lane + 0] = a0;
    wsum[wv][2 * lane + 1] = a1;
    __syncthreads();
    if (tid < 128) {
        part[(long)blockIdx.x * 128 + tid] =
            (wsum[0][tid] + wsum[1][tid]) + (wsum[2][tid] + wsum[3][tid]);
    }
}

// 1 block, 1024 threads: recompute params (nmin/nmax), deterministic reduce of
// partials (fixed slice order), uint64 (score_bits<<32|k) min == strict-< argmin.
__global__ void k_final(const float* __restrict__ mm, int mmb,
                        const float* __restrict__ part, int nblk,
                        float* __restrict__ out) {
    __shared__ float sjs[128][8];
    __shared__ float sc[128];
    __shared__ float snmin[128], snmax[128];
    __shared__ float smn[16], smx[16];
    __shared__ unsigned long long wmin[16];
    int t = threadIdx.x;

    // reduce mm partials
    float mn = INFINITY, mx = -INFINITY;
    for (int e = t; e < mmb; e += 1024) {
        mn = fminf(mn, mm[2 * e + 0]);
        mx = fmaxf(mx, mm[2 * e + 1]);
    }
    #pragma unroll
    for (int m = 32; m; m >>= 1) {
        mn = fminf(mn, __shfl_xor(mn, m, 64));
        mx = fmaxf(mx, __shfl_xor(mx, m, 64));
    }
    int wv = t >> 6;
    if ((t & 63) == 0) { smn[wv] = mn; smx[wv] = mx; }
    __syncthreads();
    if (t < 128) {
        float xmin = smn[0], xmax = smx[0];
        #pragma unroll
        for (int w = 1; w < 16; ++w) {
            xmin = fminf(xmin, smn[w]);
            xmax = fmaxf(xmax, smx[w]);
        }
        float nmi, nma;
        (void)cand_params(t, xmin, xmax, &nmi, &nma);
        snmin[t] = nmi;
        snmax[t] = nma;
    }

    // reduce per-block loss partials: candidate k = t>>3, slice j = t&7
    int k = t >> 3, j = t & 7;
    float s = 0.0f;
    for (int b = j; b < nblk; b += 8) s += part[(long)b * 128 + k];
    sjs[k][j] = s;
    __syncthreads();
    if (j == 0) {
        sc[k] = ((sjs[k][0] + sjs[k][1]) + (sjs[k][2] + sjs[k][3]))
              + ((sjs[k][4] + sjs[k][5]) + (sjs[k][6] + sjs[k][7]));
    }
    __syncthreads();
    unsigned long long key = ~0ull;
    if (t < 128) {
        key = (((unsigned long long)__float_as_uint(sc[t])) << 32) | (unsigned)t;
    }
    #pragma unroll
    for (int m = 32; m; m >>= 1) {
        unsigned long long o = __shfl_xor(key, m, 64);
        key = (o < key) ? o : key;
    }
    if ((t & 63) == 0) wmin[wv] = key;
    __syncthreads();
    if (t == 0) {
        unsigned long long best = wmin[0];
        for (int w = 1; w < 16; ++w) if (wmin[w] < best) best = wmin[w];
        int bk = (int)(best & 0x7fu);
        out[0] = snmin[bk];
        out[1] = snmax[bk];
    }
}

extern "C" void kernel_launch(void* const* d_in, const int* in_sizes, int n_in,
                              void* d_out, int out_size, void* d_ws, size_t ws_size,
                              hipStream_t stream) {
    const float* x = (const float*)d_in[0];
    int n = in_sizes[0];
    float* out = (float*)d_out;
    float* W = (float*)d_ws;

    int n4 = n >> 2;
    int mmb = (n4 + TPB - 1) / TPB;
    if (mmb > MMB) mmb = MMB;
    if (mmb < 1) mmb = 1;

    long maxblk_l = ((long)(ws_size / 4) - OFF_PART) / 128;
    int scb = SCB;
    if (maxblk_l < (long)scb) scb = (int)(maxblk_l < 1 ? 1 : maxblk_l);
    int nwc = (n + WELEM - 1) / WELEM;
    int minblk = (nwc + 3) / 4;
    if (scb > minblk) scb = minblk;   // no empty blocks
    if (scb < 1) scb = 1;

    k_minmax<<<mmb, TPB, 0, stream>>>(x, n, W + OFF_MM);
    k_score<<<scb, TPB, 0, stream>>>(x, n, W + OFF_MM, mmb, W + OFF_PART, nwc);
    k_final<<<1, 1024, 0, stream>>>(W + OFF_MM, mmb, W + OFF_PART, scb, out);
}